// Round 13
// baseline (297.831 us; speedup 1.0000x reference)
//
#include <hip/hip_runtime.h>

#define B_  8
#define S_  4096
#define D_  768
#define H_  12
#define M_  (B_ * S_)      // 32768
#define NQKV_ 2304         // 3*D
#define NTILES 12          // 768 / 64

typedef unsigned short u16;
typedef __attribute__((ext_vector_type(4))) float  f32x4;
typedef __attribute__((ext_vector_type(8))) __bf16 bf16x8;
typedef __attribute__((ext_vector_type(4))) u16    u16x4;

#define GAS __attribute__((address_space(1)))
#define LAS __attribute__((address_space(3)))

__device__ __forceinline__ u16 f2bf(float f) {
    unsigned u = __float_as_uint(f);
    u += 0x7FFF + ((u >> 16) & 1);          // round-to-nearest-even
    return (u16)(u >> 16);
}
__device__ __forceinline__ float bf2f(u16 h) {
    return __uint_as_float(((unsigned)h) << 16);
}

__device__ __forceinline__ void gload_lds16(const void* g, void* l) {
    __builtin_amdgcn_global_load_lds((const GAS void*)g, (LAS void*)l, 16, 0, 0);
}

// bijective XCD swizzle (nwg % 8 == 0): each XCD gets a contiguous work chunk
__device__ __forceinline__ int xcd_swz(int bid, int nwg) {
    return (bid & 7) * (nwg >> 3) + (bid >> 3);
}

// ---------------- cast x (f32 -> bf16) ----------------
__global__ __launch_bounds__(256) void castx_kernel(const float* __restrict__ x,
                                                    u16* __restrict__ xb) {
    const int i = blockIdx.x * 256 + threadIdx.x;
    const float4 v = ((const float4*)x)[i];
    u16x4 o;
    o.x = f2bf(v.x); o.y = f2bf(v.y); o.z = f2bf(v.z); o.w = f2bf(v.w);
    ((u16x4*)xb)[i] = o;
}

// ---------------- weight transpose+cast: W[k][n] f32 -> Wb[n][k] bf16 ----------------
__global__ __launch_bounds__(256) void wtrans_kernel(const float* __restrict__ Wq,
                                                     const float* __restrict__ Wk,
                                                     const float* __restrict__ Wv,
                                                     const float* __restrict__ Wo,
                                                     u16* __restrict__ Wb) {
    const float* W = (blockIdx.z == 0) ? Wq : (blockIdx.z == 1) ? Wk
                   : (blockIdx.z == 2) ? Wv : Wo;
    u16* O = Wb + (size_t)blockIdx.z * D_ * D_;
    __shared__ float tile[32][33];
    const int tx = threadIdx.x & 31, ty = threadIdx.x >> 5;  // 32x8
    const int k0 = blockIdx.y * 32, n0 = blockIdx.x * 32;
#pragma unroll
    for (int j = 0; j < 4; j++)
        tile[ty + j * 8][tx] = W[(size_t)(k0 + ty + j * 8) * D_ + n0 + tx];
    __syncthreads();
#pragma unroll
    for (int j = 0; j < 4; j++)
        O[(size_t)(n0 + ty + j * 8) * D_ + k0 + tx] = f2bf(tile[tx][ty + j * 8]);
}

// === 128x128 4-phase counted-vmcnt bf16 MFMA GEMM — depth x TLP (2 blk/CU) ===
// 256 threads = 4 waves (2M x 2N), per-wave C = 64x64 (acc 64 f32), BK=64.
// LDS 64 KiB = 2 buffers x (A 128rows x 128B + B 128rows x 128B).
// Schedule = R8's PROVEN 4-phase counted-vmcnt ledger, scaled:
//  ph1: read A-mlo(4)+B-nlo(4); stage A-h0(X+1)->o; MFMA q(lo,lo)
//  ph2: read B-nhi(4);          stage A-h1(X+1)->o; MFMA q(lo,hi)
//  ph3: read A-mhi(4);          stage B-h0(X+2)->c; MFMA q(hi,lo)
//  ph4: (no reads)              stage B-h1(X+2)->c; MFMA q(hi,hi); vmcnt(4)
// Ledger/wave (2 gloads per stage): at X ph4-end vmcnt(4) keeps newest 4 =
//  B(X+2), retires A(X+1)+B(X+1) -> X+1 resident after the barrier. Never
//  drains to 0 in-loop. WAR: A-h(X+1)->o after o's A last read (X-1 ph3,
//  barrier-separated); B(X+2)->c after c's B last read (X ph2). Tail stages
//  wrap (R6 lesson); vmcnt(0) drain after loop.
// Swizzle (VERIFIED 0-conflict): slot s of 128B row R holds chunk s^(R&7).
// TLP: 64 KiB + ~160 regs -> 2 INDEPENDENT blocks/CU fill each other's stalls.

#define PH_IN()                                              \
    __builtin_amdgcn_sched_barrier(0);                       \
    __builtin_amdgcn_s_barrier();                            \
    asm volatile("s_waitcnt lgkmcnt(0)" ::: "memory");       \
    __builtin_amdgcn_sched_barrier(0)

#define PH_OUT()                                             \
    __builtin_amdgcn_sched_barrier(0);                       \
    __builtin_amdgcn_s_barrier();                            \
    __builtin_amdgcn_sched_barrier(0)

#define PH_OUT_VM(N)                                         \
    __builtin_amdgcn_sched_barrier(0);                       \
    asm volatile("s_waitcnt vmcnt(" #N ")" ::: "memory");    \
    __builtin_amdgcn_s_barrier();                            \
    __builtin_amdgcn_sched_barrier(0)

#define MFMA_Q(AF, BF, MO, NO)                                               \
    __builtin_amdgcn_s_setprio(1);                                           \
    _Pragma("unroll") for (int mi = 0; mi < 2; ++mi)                         \
        _Pragma("unroll") for (int ni = 0; ni < 2; ++ni)                     \
            _Pragma("unroll") for (int kh = 0; kh < 2; ++kh)                 \
                acc[mi + MO][ni + NO] =                                      \
                    __builtin_amdgcn_mfma_f32_16x16x32_bf16(                 \
                        AF[mi][kh], BF[ni][kh], acc[mi + MO][ni + NO], 0, 0, 0); \
    __builtin_amdgcn_s_setprio(0)

#define RD(p, imm) (*(const bf16x8*)((p) + (imm)))

template <int MODE>
__global__ __launch_bounds__(256, 2) void gemm4_kernel(
    const u16* __restrict__ A, const u16* __restrict__ Wb,
    const float* __restrict__ b0, const float* __restrict__ b1,
    const float* __restrict__ b2,
    u16* __restrict__ outb, const u16* __restrict__ xres) {
    extern __shared__ char lds[];    // 65536 B

    const int t = threadIdx.x;
    const int w = t >> 6, l = t & 63;
    const int wm = w >> 1, wn = w & 1;

    const int NTN = (MODE == 0) ? 18 : 6;
    const int work = xcd_swz(blockIdx.x, gridDim.x);
    const int mt = work / NTN, nt = work % NTN;   // nt fastest: A L2-reuse in XCD
    const int m0 = mt * 128;
    const int col0 = nt * 128;                    // output column base
    const int widx = (MODE == 0) ? (nt / 6) : 3;
    const int n0w  = (MODE == 0) ? (nt % 6) * 128 : col0;  // weight-row base

    // ---- staging geometry (pre-swizzled source; 128B rows, 8 slots) ----
    // gload g covers 8 rows; lane l -> row base+(l>>3), slot l&7,
    // fetches global chunk (l&7)^(l>>3)  (base rows are multiples of 8).
    const int lrow = l >> 3;
    const int schunk = (l & 7) ^ lrow;
    const u16* AsrcB = A + (size_t)(m0 + w * 16 + lrow) * D_ + schunk * 8;
    const u16* BsrcB = Wb + (size_t)widx * (D_ * D_)
                          + (size_t)(n0w + w * 16 + lrow) * D_ + schunk * 8;
    char* const dstA = lds + w * 2048;            // + bufoff + h*8192 + g*1024
    char* const dstB = lds + 16384 + w * 2048;

    // stage A half h (rows h*64..h*64+63) of K-tile tk into buffer byte-off bo
    auto STAGE_A = [&](int h, int tk, int bo) {
        const u16* s = AsrcB + (size_t)(h * 64) * D_ + tk * 64;
        char* d = dstA + bo + h * 8192;
        gload_lds16(s, d);
        gload_lds16(s + 8 * D_, d + 1024);
    };
    auto STAGE_B = [&](int h, int tk, int bo) {
        const u16* s = BsrcB + (size_t)(h * 64) * D_ + tk * 64;
        char* d = dstB + bo + h * 8192;
        gload_lds16(s, d);
        gload_lds16(s + 8 * D_, d + 1024);
    };

    // ---- ds_read geometry (swizzled slot; verified pattern) ----
    const int fr = l & 15;
    const int ck0 = (((l >> 4) ^ (fr & 7)) << 4);        // kh0 slot byte
    const int ck1 = ((((l >> 4) + 4) ^ (fr & 7)) << 4);  // kh1 slot byte
    const char* aB = lds + (wm * 64 + fr) * 128;          // +buf +mi*2048
    const char* bB = lds + 16384 + (wn * 64 + fr) * 128;  // +buf +ni*2048

    f32x4 acc[4][4];
#pragma unroll
    for (int i = 0; i < 4; i++)
#pragma unroll
        for (int j = 0; j < 4; j++) acc[i][j] = (f32x4){0.f, 0.f, 0.f, 0.f};

    bf16x8 Amlo[2][2], Amhi[2][2], Bnlo[2][2], Bnhi[2][2];

    // ---- prologue: A(0),B(0)->buf0 (8 gl), B(1)->buf1 (4 gl); vmcnt(4) ----
    STAGE_A(0, 0, 0); STAGE_A(1, 0, 0); STAGE_B(0, 0, 0); STAGE_B(1, 0, 0);
    STAGE_B(0, 1, 32768); STAGE_B(1, 1, 32768);
    __builtin_amdgcn_sched_barrier(0);
    asm volatile("s_waitcnt vmcnt(4)" ::: "memory");   // tile0 landed; B(1) in flight
    __builtin_amdgcn_s_barrier();
    __builtin_amdgcn_sched_barrier(0);

#pragma unroll
    for (int X = 0; X < NTILES; ++X) {
        const int cb = (X & 1) * 32768;      // buffer holding tile X
        const int ob = cb ^ 32768;           // buffer holding tile X+1
        const int t1 = (X + 1 < NTILES) ? X + 1 : X + 1 - NTILES;  // wrapped
        const int t2 = (X + 2 < NTILES) ? X + 2 : X + 2 - NTILES;

        // ---- ph1: read A-mlo + B-nlo; stage A-h0(t1)->o; MFMA q(lo,lo) ----
#pragma unroll
        for (int mi = 0; mi < 2; ++mi) {
            Amlo[mi][0] = RD(aB, cb + mi * 2048 + ck0);
            Amlo[mi][1] = RD(aB, cb + mi * 2048 + ck1);
        }
#pragma unroll
        for (int ni = 0; ni < 2; ++ni) {
            Bnlo[ni][0] = RD(bB, cb + ni * 2048 + ck0);
            Bnlo[ni][1] = RD(bB, cb + ni * 2048 + ck1);
        }
        STAGE_A(0, t1, ob);
        PH_IN();
        MFMA_Q(Amlo, Bnlo, 0, 0);
        PH_OUT();

        // ---- ph2: read B-nhi; stage A-h1(t1)->o; MFMA q(lo,hi) ----
#pragma unroll
        for (int ni = 0; ni < 2; ++ni) {
            Bnhi[ni][0] = RD(bB, cb + (ni + 2) * 2048 + ck0);
            Bnhi[ni][1] = RD(bB, cb + (ni + 2) * 2048 + ck1);
        }
        STAGE_A(1, t1, ob);
        PH_IN();
        MFMA_Q(Amlo, Bnhi, 0, 2);
        PH_OUT();

        // ---- ph3: read A-mhi; stage B-h0(t2)->c; MFMA q(hi,lo) ----
#pragma unroll
        for (int mi = 0; mi < 2; ++mi) {
            Amhi[mi][0] = RD(aB, cb + (mi + 2) * 2048 + ck0);
            Amhi[mi][1] = RD(aB, cb + (mi + 2) * 2048 + ck1);
        }
        STAGE_B(0, t2, cb);
        PH_IN();
        MFMA_Q(Amhi, Bnlo, 2, 0);
        PH_OUT();

        // ---- ph4: no reads; stage B-h1(t2)->c; MFMA q(hi,hi); vmcnt(4) ----
        STAGE_B(1, t2, cb);
        PH_IN();
        MFMA_Q(Amhi, Bnhi, 2, 2);
        PH_OUT_VM(4);
    }
    asm volatile("s_waitcnt vmcnt(0)" ::: "memory");   // drain wrapped stages

    // ---- epilogue ----
    const int crow0 = m0 + wm * 64 + ((l >> 4) << 2);
    const int ccol0 = col0 + wn * 64 + fr;
    if (MODE == 0) {
        const float* bias = (widx == 0) ? b0 : (widx == 1) ? b1 : b2;
        const int bcol0 = ccol0 - widx * D_;
#pragma unroll
        for (int mi = 0; mi < 4; ++mi)
#pragma unroll
            for (int ni = 0; ni < 4; ++ni) {
                const float bv = bias[bcol0 + ni * 16];
#pragma unroll
                for (int r = 0; r < 4; ++r)
                    outb[(size_t)(crow0 + mi * 16 + r) * NQKV_ + ccol0 + ni * 16] =
                        f2bf(acc[mi][ni][r] + bv);
            }
    } else {
#pragma unroll
        for (int mi = 0; mi < 4; ++mi)
#pragma unroll
            for (int ni = 0; ni < 4; ++ni) {
                const int col = ccol0 + ni * 16;
                const float bv = b0[col];
#pragma unroll
                for (int r = 0; r < 4; ++r) {
                    const size_t idx = (size_t)(crow0 + mi * 16 + r) * D_ + col;
                    outb[idx] = f2bf(acc[mi][ni][r] + bv + bf2f(xres[idx]));
                }
            }
    }
}

// ---------------- local attention: one wave per (m, head-quad) ----------------
__global__ __launch_bounds__(256) void attn_kernel(const u16* __restrict__ QKV,
                                                   const float* __restrict__ bk,
                                                   const float* __restrict__ bv,
                                                   u16* __restrict__ att) {
    const int gw = xcd_swz(blockIdx.x, gridDim.x) * 4 + (threadIdx.x >> 6);
    const int l  = threadIdx.x & 63;
    const int hq = gw % 3;             // head-quad index
    const int m  = gw / 3;
    const int s  = m & (S_ - 1);
    const int col = hq * 256 + l * 4;
    const u16* base = QKV + (size_t)m * NQKV_;

    const u16x4 qv = *(const u16x4*)(base + col);
    float qf[4];
#pragma unroll
    for (int j = 0; j < 4; j++) qf[j] = bf2f(qv[j]);

    float sc[5];
#pragma unroll
    for (int i = 0; i < 5; i++) {
        const int sp = s + i - 2;
        float p;
        if (sp >= 0 && sp < S_) {
            const u16x4 kv = *(const u16x4*)(base + (i - 2) * NQKV_ + D_ + col);
            p = qf[0] * bf2f(kv[0]) + qf[1] * bf2f(kv[1])
              + qf[2] * bf2f(kv[2]) + qf[3] * bf2f(kv[3]);
        } else {
            const float4 kb = *(const float4*)(bk + col);
            p = qf[0] * kb.x + qf[1] * kb.y + qf[2] * kb.z + qf[3] * kb.w;
        }
#pragma unroll
        for (int off = 1; off < 16; off <<= 1) p += __shfl_xor(p, off, 64);
        sc[i] = p * 0.125f;
    }
    float mx = sc[0];
#pragma unroll
    for (int i = 1; i < 5; i++) mx = fmaxf(mx, sc[i]);
    float e[5], sum = 0.f;
#pragma unroll
    for (int i = 0; i < 5; i++) { e[i] = __expf(sc[i] - mx); sum += e[i]; }
    const float inv = 1.f / sum;

    float o[4] = {0.f, 0.f, 0.f, 0.f};
#pragma unroll
    for (int i = 0; i < 5; i++) {
        const float wgt = e[i] * inv;
        const int sp = s + i - 2;
        if (sp >= 0 && sp < S_) {
            const u16x4 vv = *(const u16x4*)(base + (i - 2) * NQKV_ + 2 * D_ + col);
#pragma unroll
            for (int j = 0; j < 4; j++) o[j] += wgt * bf2f(vv[j]);
        } else {
            const float4 vb = *(const float4*)(bv + col);
            o[0] += wgt * vb.x; o[1] += wgt * vb.y;
            o[2] += wgt * vb.z; o[3] += wgt * vb.w;
        }
    }
    u16x4 ov;
#pragma unroll
    for (int j = 0; j < 4; j++) ov[j] = f2bf(o[j]);
    *(u16x4*)(att + (size_t)m * D_ + col) = ov;
}

// ---------------- LayerNorm over rows of 768 (bf16 in, f32 out) ----------------
__global__ __launch_bounds__(256) void ln_kernel(const u16* __restrict__ Yb,
                                                 const float* __restrict__ gamma,
                                                 const float* __restrict__ beta,
                                                 float* __restrict__ out) {
    const int row = blockIdx.x;
    const u16* r = Yb + (size_t)row * D_;
    const int t = threadIdx.x;
    const float v0 = bf2f(r[t]), v1 = bf2f(r[t + 256]), v2 = bf2f(r[t + 512]);
    float s  = v0 + v1 + v2;
    float s2 = v0 * v0 + v1 * v1 + v2 * v2;
#pragma unroll
    for (int off = 32; off > 0; off >>= 1) {
        s  += __shfl_xor(s,  off, 64);
        s2 += __shfl_xor(s2, off, 64);
    }
    __shared__ float red[8];
    const int w = t >> 6, l = t & 63;
    if (l == 0) { red[w] = s; red[4 + w] = s2; }
    __syncthreads();
    s  = red[0] + red[1] + red[2] + red[3];
    s2 = red[4] + red[5] + red[6] + red[7];
    const float mu  = s * (1.f / 768.f);
    const float var = s2 * (1.f / 768.f) - mu * mu;
    const float inv = rsqrtf(var + 1e-5f);
    float* o = out + (size_t)row * D_;
    o[t]       = (v0 - mu) * inv * gamma[t]       + beta[t];
    o[t + 256] = (v1 - mu) * inv * gamma[t + 256] + beta[t + 256];
    o[t + 512] = (v2 - mu) * inv * gamma[t + 512] + beta[t + 512];
}

extern "C" void kernel_launch(void* const* d_in, const int* in_sizes, int n_in,
                              void* d_out, int out_size, void* d_ws, size_t ws_size,
                              hipStream_t stream) {
    const float* x     = (const float*)d_in[0];
    const float* Wq    = (const float*)d_in[1];
    const float* bq    = (const float*)d_in[2];
    const float* Wk    = (const float*)d_in[3];
    const float* bk    = (const float*)d_in[4];
    const float* Wv    = (const float*)d_in[5];
    const float* bv    = (const float*)d_in[6];
    const float* Wo    = (const float*)d_in[7];
    const float* bo    = (const float*)d_in[8];
    const float* gamma = (const float*)d_in[9];
    const float* beta  = (const float*)d_in[10];

    char* ws = (char*)d_ws;
    u16*   Wb  = (u16*)ws;                                  //  4,718,592 B
    u16*   xb  = (u16*)(ws + 4718592);                      // 50,331,648 B (stays live)
    u16*   QKV = (u16*)(ws + 4718592 + 50331648);           // 150,994,944 B
    u16*   yb  = QKV;                                       // reuse after attn
    u16*   att = (u16*)d_out;                               // scratch in d_out

    (void)hipFuncSetAttribute(reinterpret_cast<const void*>(&gemm4_kernel<0>),
                              hipFuncAttributeMaxDynamicSharedMemorySize, 65536);
    (void)hipFuncSetAttribute(reinterpret_cast<const void*>(&gemm4_kernel<1>),
                              hipFuncAttributeMaxDynamicSharedMemorySize, 65536);

    castx_kernel<<<(M_ * D_) / (256 * 4), 256, 0, stream>>>(x, xb);
    wtrans_kernel<<<dim3(24, 24, 4), 256, 0, stream>>>(Wq, Wk, Wv, Wo, Wb);
    gemm4_kernel<0><<<(M_ / 128) * 18, 256, 65536, stream>>>(xb, Wb, bq, bk, bv,
                                                             QKV, nullptr);
    attn_kernel<<<(M_ * 3) / 4, 256, 0, stream>>>(QKV, bk, bv, att);
    gemm4_kernel<1><<<(M_ / 128) * 6, 256, 65536, stream>>>(att, Wb, bo, nullptr, nullptr,
                                                            yb, xb);
    ln_kernel<<<M_, 256, 0, stream>>>(yb, gamma, beta, (float*)d_out);
}